// Round 1
// baseline (312.745 us; speedup 1.0000x reference)
//
#include <hip/hip_runtime.h>
#include <hip/hip_bf16.h>
#include <cstdint>
#include <cstddef>

#define ALPHA 0.2f
#define LOG2E 1.4426950408889634f

using f32x4 = __attribute__((ext_vector_type(4))) float;
using s16x8 = __attribute__((ext_vector_type(8))) short;

__device__ __forceinline__ unsigned short f2bf(float f) {
  // round-to-nearest-even fp32 -> bf16 (no NaN/Inf in this workload)
  unsigned u = __float_as_uint(f);
  u = (u + 0x7fffu + ((u >> 16) & 1u)) >> 16;
  return (unsigned short)u;
}

// ---------------------------------------------------------------------------
// Kernel 1: Wh = h @ W (fp32), s1 = Wh·a1, s2 = Wh·a2,
//           WhT[b][c][n] = bf16(Wh) stored transposed for kernel 2.
// Grid: 512 blocks x 256 threads; block handles 64 consecutive flat rows.
// ---------------------------------------------------------------------------
__global__ __launch_bounds__(256) void k1_proj(
    const float* __restrict__ h, const float* __restrict__ W,
    const float* __restrict__ a1, const float* __restrict__ a2,
    unsigned short* __restrict__ whT, float* __restrict__ s1,
    float* __restrict__ s2) {
  __shared__ __align__(16) float h_lds[64 * 64];
  __shared__ __align__(16) float W_lds[64 * 64];
  __shared__ __align__(16) unsigned short t_lds[64 * 64];  // swizzled [c][n]

  const int t = threadIdx.x;
  const int c = t & 63;        // output channel per lane
  const int w = t >> 6;        // wave id, owns rows w*16..w*16+15
  const int row0 = blockIdx.x * 64;  // flat row base (b*2048 + n), tile-aligned

  const float4* hg = (const float4*)(h + (size_t)row0 * 64);
  #pragma unroll
  for (int r = 0; r < 4; ++r) {
    ((float4*)h_lds)[t + r * 256] = hg[t + r * 256];
    ((float4*)W_lds)[t + r * 256] = ((const float4*)W)[t + r * 256];
  }
  const float a1v = a1[c];
  const float a2v = a2[c];
  __syncthreads();

  float acc[16];
  #pragma unroll
  for (int r = 0; r < 16; ++r) acc[r] = 0.0f;

  #pragma unroll
  for (int kc = 0; kc < 16; ++kc) {
    const float w0 = W_lds[(kc * 4 + 0) * 64 + c];
    const float w1 = W_lds[(kc * 4 + 1) * 64 + c];
    const float w2 = W_lds[(kc * 4 + 2) * 64 + c];
    const float w3 = W_lds[(kc * 4 + 3) * 64 + c];
    #pragma unroll
    for (int r = 0; r < 16; ++r) {
      const float4 hv = ((const float4*)(h_lds + (w * 16 + r) * 64))[kc];
      acc[r] = fmaf(hv.x, w0, acc[r]);
      acc[r] = fmaf(hv.y, w1, acc[r]);
      acc[r] = fmaf(hv.z, w2, acc[r]);
      acc[r] = fmaf(hv.w, w3, acc[r]);
    }
  }

  // s1/s2 row reductions (butterfly over 64 lanes)
  #pragma unroll
  for (int r = 0; r < 16; ++r) {
    float v1 = acc[r] * a1v;
    float v2 = acc[r] * a2v;
    #pragma unroll
    for (int s = 1; s < 64; s <<= 1) {
      v1 += __shfl_xor(v1, s, 64);
      v2 += __shfl_xor(v2, s, 64);
    }
    if (c == 0) {
      s1[row0 + w * 16 + r] = v1;
      s2[row0 + w * 16 + r] = v2;
    }
  }

  // Transpose via LDS (swizzled) then coalesced global store of WhT (bf16).
  // Element (c, n_loc) lives at LDS byte  c*128 + ((n_loc*2) ^ ((c&7)<<4)).
  #pragma unroll
  for (int hh = 0; hh < 2; ++hh) {
    uint4 pk;
    unsigned* pw = (unsigned*)&pk;
    #pragma unroll
    for (int q = 0; q < 4; ++q) {
      const unsigned lo = f2bf(acc[hh * 8 + q * 2 + 0]);
      const unsigned hi = f2bf(acc[hh * 8 + q * 2 + 1]);
      pw[q] = lo | (hi << 16);
    }
    const int off = c * 128 + ((w * 32 + hh * 16) ^ ((c & 7) << 4));
    *(uint4*)((char*)t_lds + off) = pk;
  }
  __syncthreads();

  const int b = row0 >> 11;     // row0 / 2048
  const int n0 = row0 & 2047;
  #pragma unroll
  for (int q = 0; q < 2; ++q) {
    const int chunk = q * 256 + t;
    const int cc = chunk >> 3;
    const int w8 = (chunk & 7) * 16;
    const uint4 v =
        *(const uint4*)((const char*)t_lds + cc * 128 + (w8 ^ ((cc & 7) << 4)));
    *(uint4*)((char*)whT + ((size_t)(b * 64 + cc) * 2048 + n0) * 2 + w8) = v;
  }
}

// ---------------------------------------------------------------------------
// Kernel 2: flash-style attention over precomputed rank-1 scores + bias.
// Grid: 512 blocks (16 batches x 32 i-tiles) x 256 threads (4 waves x 16 rows).
// Online softmax over 32 j-tiles of 64; PV via mfma_f32_16x16x32_bf16.
// ---------------------------------------------------------------------------
__global__ __launch_bounds__(256) void k2_attn(
    const float* __restrict__ bias, const unsigned short* __restrict__ whT,
    const float* __restrict__ s1g, const float* __restrict__ s2g,
    float* __restrict__ out) {
  __shared__ __align__(16) unsigned short buf[2][4096];  // 2 x 8KB swizzled [c][j]
  __shared__ __align__(16) float s2_lds[2048];

  const int t = threadIdx.x;
  const int lane = t & 63;
  const int w = t >> 6;
  const int arow = lane & 15;   // A-frag / softmax row within wave's 16
  const int kgrp = lane >> 4;   // 0..3  (k-group of 8)
  const int bidx = blockIdx.x;
  const int b = bidx >> 5;
  const int i0 = (bidx & 31) * 64;
  const int gi = i0 + w * 16 + arow;  // row index within batch

  const float s1v = s1g[b * 2048 + gi];

  // stage s2[b][:] (8KB) once
  #pragma unroll
  for (int q = 0; q < 2; ++q)
    ((float4*)s2_lds)[t + q * 256] =
        ((const float4*)(s2g + b * 2048))[t + q * 256];

  const char* whT_b = (const char*)whT + (size_t)b * 64 * 2048 * 2;
  const float* bias_p = bias + ((size_t)b * 2048 + gi) * 2048 + kgrp * 8;

  // staging geometry (2 x 16B chunks per thread per tile)
  const int cc0 = t >> 3,         w80 = (t & 7) * 16;
  const int cc1 = (256 + t) >> 3, w81 = (t & 7) * 16;

  uint4 stg0, stg1;
  float4 bcur[4], bnext[4];

  auto stage_load = [&](int jt) {
    stg0 = *(const uint4*)(whT_b + ((size_t)cc0 * 2048 + jt * 64) * 2 + w80);
    stg1 = *(const uint4*)(whT_b + ((size_t)cc1 * 2048 + jt * 64) * 2 + w81);
  };
  auto stage_write = [&](int pp) {
    *(uint4*)((char*)buf[pp] + cc0 * 128 + (w80 ^ ((cc0 & 7) << 4))) = stg0;
    *(uint4*)((char*)buf[pp] + cc1 * 128 + (w81 ^ ((cc1 & 7) << 4))) = stg1;
  };
  auto bias_load = [&](float4* dst, int jt) {
    const float* p = bias_p + jt * 64;
    dst[0] = *(const float4*)(p);
    dst[1] = *(const float4*)(p + 4);
    dst[2] = *(const float4*)(p + 32);
    dst[3] = *(const float4*)(p + 36);
  };

  stage_load(0);
  bias_load(bcur, 0);
  stage_write(0);
  __syncthreads();

  f32x4 acc[4];
  #pragma unroll
  for (int ct = 0; ct < 4; ++ct) acc[ct] = (f32x4){0.f, 0.f, 0.f, 0.f};
  float m = -INFINITY, l = 0.0f;

  for (int jt = 0; jt < 32; ++jt) {
    const int pp = jt & 1;
    if (jt < 31) {
      stage_load(jt + 1);       // next WhT tile -> regs (written after compute)
      bias_load(bnext, jt + 1); // next bias tile -> regs (latency hidden)
    }

    // e[i, j] = leakyrelu(s1_i + s2_j) + bias_ij   (16 values per lane)
    float ev[16];
    #pragma unroll
    for (int f = 0; f < 2; ++f) {
      const float4 sa = *(const float4*)(s2_lds + jt * 64 + f * 32 + kgrp * 8);
      const float4 sb =
          *(const float4*)(s2_lds + jt * 64 + f * 32 + kgrp * 8 + 4);
      const float4 ba = bcur[f * 2 + 0];
      const float4 bb = bcur[f * 2 + 1];
      const float s2v[8] = {sa.x, sa.y, sa.z, sa.w, sb.x, sb.y, sb.z, sb.w};
      const float bv[8] = {ba.x, ba.y, ba.z, ba.w, bb.x, bb.y, bb.z, bb.w};
      #pragma unroll
      for (int e = 0; e < 8; ++e) {
        float x = s1v + s2v[e];
        x = x > 0.0f ? x : ALPHA * x;
        ev[f * 8 + e] = x + bv[e];
      }
    }

    // row max (in-lane 16, then across the 4 lanes sharing this row)
    float mx = ev[0];
    #pragma unroll
    for (int e = 1; e < 16; ++e) mx = fmaxf(mx, ev[e]);
    mx = fmaxf(mx, __shfl_xor(mx, 16, 64));
    mx = fmaxf(mx, __shfl_xor(mx, 32, 64));
    const float mnew = fmaxf(m, mx);
    const float corr = exp2f((m - mnew) * LOG2E);  // m=-inf first iter -> 0

    float ps = 0.0f;
    s16x8 afrag[2];
    #pragma unroll
    for (int f = 0; f < 2; ++f) {
      #pragma unroll
      for (int e = 0; e < 8; ++e) {
        const float p = exp2f((ev[f * 8 + e] - mnew) * LOG2E);
        ps += p;
        afrag[f][e] = (short)f2bf(p);
      }
    }
    ps += __shfl_xor(ps, 16, 64);
    ps += __shfl_xor(ps, 32, 64);
    l = l * corr + ps;
    m = mnew;

    // rescale accumulator: C-frag rows are kgrp*4+r; corr for row r sits at lane r
    float fc[4];
    #pragma unroll
    for (int r = 0; r < 4; ++r) fc[r] = __shfl(corr, kgrp * 4 + r, 64);
    #pragma unroll
    for (int ct = 0; ct < 4; ++ct) {
      acc[ct][0] *= fc[0];
      acc[ct][1] *= fc[1];
      acc[ct][2] *= fc[2];
      acc[ct][3] *= fc[3];
    }

    // PV: acc[16 rows x 64 cols] += P[16x64] @ Wh[64x64]
    #pragma unroll
    for (int ct = 0; ct < 4; ++ct) {
      const int cc = ct * 16 + arow;
      #pragma unroll
      for (int f = 0; f < 2; ++f) {
        const s16x8 bfrag = *(const s16x8*)((const char*)buf[pp] + cc * 128 +
                                            ((f * 64 + kgrp * 16) ^
                                             ((cc & 7) << 4)));
        // s_nop 1 covers VALU-write -> MFMA-read wait states (inline asm is
        // opaque to the hazard recognizer); chained same-acc MFMAs are legal.
        asm("s_nop 1\n\t"
            "v_mfma_f32_16x16x32_bf16 %0, %1, %2, %0"
            : "+v"(acc[ct])
            : "v"(afrag[f]), "v"(bfrag));
      }
    }

    if (jt < 31) {
      stage_write((jt + 1) & 1);  // other buffer; current readers unaffected
      bcur[0] = bnext[0]; bcur[1] = bnext[1];
      bcur[2] = bnext[2]; bcur[3] = bnext[3];
    }
    __syncthreads();
  }

  // MFMA-write -> VALU-read safety margin before epilogue reads of acc
  asm volatile("s_nop 7\n\ts_nop 7" ::: "memory");

  const float linv = 1.0f / l;
  #pragma unroll
  for (int r = 0; r < 4; ++r) {
    const float li = __shfl(linv, kgrp * 4 + r, 64);
    float* op = out + ((size_t)b * 2048 + i0 + w * 16 + kgrp * 4 + r) * 64;
    #pragma unroll
    for (int ct = 0; ct < 4; ++ct) op[ct * 16 + arow] = acc[ct][r] * li;
  }
}

// ---------------------------------------------------------------------------
extern "C" void kernel_launch(void* const* d_in, const int* in_sizes, int n_in,
                              void* d_out, int out_size, void* d_ws,
                              size_t ws_size, hipStream_t stream) {
  const float* h = (const float*)d_in[0];
  const float* bias = (const float*)d_in[1];
  const float* W = (const float*)d_in[2];
  const float* a1 = (const float*)d_in[3];
  const float* a2 = (const float*)d_in[4];
  float* out = (float*)d_out;

  char* ws = (char*)d_ws;
  unsigned short* whT = (unsigned short*)ws;             // 16*64*2048*2 = 4 MiB
  float* s1 = (float*)(ws + 4 * 1024 * 1024);            // 128 KiB
  float* s2 = (float*)(ws + 4 * 1024 * 1024 + 128 * 1024);  // 128 KiB

  k1_proj<<<dim3(512), dim3(256), 0, stream>>>(h, W, a1, a2, whT, s1, s2);
  k2_attn<<<dim3(512), dim3(256), 0, stream>>>(bias, whT, s1, s2, out);
}

// Round 2
// 94.572 us; speedup vs baseline: 3.3069x; 3.3069x over previous
//
#include <hip/hip_runtime.h>
#include <hip/hip_bf16.h>
#include <cstdint>
#include <cstddef>

#define ALPHA 0.2f
#define LOG2E 1.4426950408889634f

using f32x4 = __attribute__((ext_vector_type(4))) float;
using s16x8 = __attribute__((ext_vector_type(8))) short;

__device__ __forceinline__ unsigned f2bf(float f) {
  // round-to-nearest-even fp32 -> bf16 (no NaN/Inf in this workload)
  unsigned u = __float_as_uint(f);
  u = (u + 0x7fffu + ((u >> 16) & 1u)) >> 16;
  return u;
}

// ---------------------------------------------------------------------------
// Kernel 1: Wh = h @ W (fp32), s1 = Wh·a1, s2 = Wh·a2,
//           WhT[b][c][n] = bf16(Wh) stored transposed for kernel 2.
// Grid: 512 blocks x 256 threads; block handles 64 consecutive flat rows.
// R2 fix: outer k-loop NOT unrolled (R1 fully unrolled 16x16 -> 256 VGPR +
// 2.4 KB/thread scratch spill -> 310 MB of spill writes, 267 us). No
// address-taken locals (scratch trigger).
// ---------------------------------------------------------------------------
__global__ __launch_bounds__(256) void k1_proj(
    const float* __restrict__ h, const float* __restrict__ W,
    const float* __restrict__ a1, const float* __restrict__ a2,
    unsigned short* __restrict__ whT, float* __restrict__ s1,
    float* __restrict__ s2) {
  __shared__ __align__(16) float h_lds[64 * 64];           // [n_loc][k]
  __shared__ __align__(16) float W_lds[64 * 64];           // [k][c]
  __shared__ __align__(16) unsigned short t_lds[64 * 64];  // swizzled [c][n]

  const int t = threadIdx.x;
  const int c = t & 63;        // output channel per lane
  const int w = t >> 6;        // wave id, owns rows w*16..w*16+15
  const int row0 = blockIdx.x * 64;  // flat row base (b*2048 + n), tile-aligned

  const float4* hg = (const float4*)(h + (size_t)row0 * 64);
  #pragma unroll
  for (int r = 0; r < 4; ++r) {
    ((float4*)h_lds)[t + r * 256] = hg[t + r * 256];
    ((float4*)W_lds)[t + r * 256] = ((const float4*)W)[t + r * 256];
  }
  const float a1v = a1[c];
  const float a2v = a2[c];
  __syncthreads();

  float acc[16];
  #pragma unroll
  for (int r = 0; r < 16; ++r) acc[r] = 0.0f;

  // k-blocked: 16 iterations of 4-wide k. Per iteration: 4 scalar W reads
  // (stride-1 across lanes, conflict-free), 16 float4 h reads (wave-uniform
  // address -> LDS broadcast), 64 FMA. ~60 live VGPRs.
  #pragma unroll 1
  for (int kc = 0; kc < 16; ++kc) {
    const float w0 = W_lds[(kc * 4 + 0) * 64 + c];
    const float w1 = W_lds[(kc * 4 + 1) * 64 + c];
    const float w2 = W_lds[(kc * 4 + 2) * 64 + c];
    const float w3 = W_lds[(kc * 4 + 3) * 64 + c];
    #pragma unroll
    for (int r = 0; r < 16; ++r) {
      const float4 hv = *(const float4*)(h_lds + (w * 16 + r) * 64 + kc * 4);
      acc[r] = fmaf(hv.x, w0, acc[r]);
      acc[r] = fmaf(hv.y, w1, acc[r]);
      acc[r] = fmaf(hv.z, w2, acc[r]);
      acc[r] = fmaf(hv.w, w3, acc[r]);
    }
  }

  // s1/s2 row reductions (butterfly over 64 lanes)
  #pragma unroll 1
  for (int r = 0; r < 16; ++r) {
    float v1 = acc[r] * a1v;
    float v2 = acc[r] * a2v;
    #pragma unroll
    for (int s = 1; s < 64; s <<= 1) {
      v1 += __shfl_xor(v1, s, 64);
      v2 += __shfl_xor(v2, s, 64);
    }
    if (c == 0) {
      s1[row0 + w * 16 + r] = v1;
      s2[row0 + w * 16 + r] = v2;
    }
  }

  // Transpose via LDS (swizzled) then coalesced global store of WhT (bf16).
  // Element (c, n_loc) lives at LDS byte  c*128 + ((n_loc*2) ^ ((c&7)<<4)).
  #pragma unroll
  for (int hh = 0; hh < 2; ++hh) {
    uint4 pk;
    pk.x = f2bf(acc[hh * 8 + 0]) | (f2bf(acc[hh * 8 + 1]) << 16);
    pk.y = f2bf(acc[hh * 8 + 2]) | (f2bf(acc[hh * 8 + 3]) << 16);
    pk.z = f2bf(acc[hh * 8 + 4]) | (f2bf(acc[hh * 8 + 5]) << 16);
    pk.w = f2bf(acc[hh * 8 + 6]) | (f2bf(acc[hh * 8 + 7]) << 16);
    const int off = c * 128 + ((w * 32 + hh * 16) ^ ((c & 7) << 4));
    *(uint4*)((char*)t_lds + off) = pk;
  }
  __syncthreads();

  const int b = row0 >> 11;     // row0 / 2048
  const int n0 = row0 & 2047;
  #pragma unroll
  for (int q = 0; q < 2; ++q) {
    const int chunk = q * 256 + t;
    const int cc = chunk >> 3;
    const int w8 = (chunk & 7) * 16;
    const uint4 v =
        *(const uint4*)((const char*)t_lds + cc * 128 + (w8 ^ ((cc & 7) << 4)));
    *(uint4*)((char*)whT + ((size_t)(b * 64 + cc) * 2048 + n0) * 2 + w8) = v;
  }
}

// ---------------------------------------------------------------------------
// Kernel 2: flash-style attention over precomputed rank-1 scores + bias.
// Grid: 512 blocks (16 batches x 32 i-tiles) x 256 threads (4 waves x 16 rows).
// Online softmax over 32 j-tiles of 64; PV via mfma_f32_16x16x32_bf16.
// R1 measured ~45 us ~= 94% of the 268 MB bias-read roofline -> unchanged.
// ---------------------------------------------------------------------------
__global__ __launch_bounds__(256) void k2_attn(
    const float* __restrict__ bias, const unsigned short* __restrict__ whT,
    const float* __restrict__ s1g, const float* __restrict__ s2g,
    float* __restrict__ out) {
  __shared__ __align__(16) unsigned short buf[2][4096];  // 2 x 8KB swizzled [c][j]
  __shared__ __align__(16) float s2_lds[2048];

  const int t = threadIdx.x;
  const int lane = t & 63;
  const int w = t >> 6;
  const int arow = lane & 15;   // A-frag / softmax row within wave's 16
  const int kgrp = lane >> 4;   // 0..3  (k-group of 8)
  const int bidx = blockIdx.x;
  const int b = bidx >> 5;
  const int i0 = (bidx & 31) * 64;
  const int gi = i0 + w * 16 + arow;  // row index within batch

  const float s1v = s1g[b * 2048 + gi];

  // stage s2[b][:] (8KB) once
  #pragma unroll
  for (int q = 0; q < 2; ++q)
    ((float4*)s2_lds)[t + q * 256] =
        ((const float4*)(s2g + b * 2048))[t + q * 256];

  const char* whT_b = (const char*)whT + (size_t)b * 64 * 2048 * 2;
  const float* bias_p = bias + ((size_t)b * 2048 + gi) * 2048 + kgrp * 8;

  // staging geometry (2 x 16B chunks per thread per tile)
  const int cc0 = t >> 3,         w80 = (t & 7) * 16;
  const int cc1 = (256 + t) >> 3, w81 = (t & 7) * 16;

  uint4 stg0, stg1;
  float4 bcur[4], bnext[4];

  auto stage_load = [&](int jt) {
    stg0 = *(const uint4*)(whT_b + ((size_t)cc0 * 2048 + jt * 64) * 2 + w80);
    stg1 = *(const uint4*)(whT_b + ((size_t)cc1 * 2048 + jt * 64) * 2 + w81);
  };
  auto stage_write = [&](int pp) {
    *(uint4*)((char*)buf[pp] + cc0 * 128 + (w80 ^ ((cc0 & 7) << 4))) = stg0;
    *(uint4*)((char*)buf[pp] + cc1 * 128 + (w81 ^ ((cc1 & 7) << 4))) = stg1;
  };
  auto bias_load = [&](float4* dst, int jt) {
    const float* p = bias_p + jt * 64;
    dst[0] = *(const float4*)(p);
    dst[1] = *(const float4*)(p + 4);
    dst[2] = *(const float4*)(p + 32);
    dst[3] = *(const float4*)(p + 36);
  };

  stage_load(0);
  bias_load(bcur, 0);
  stage_write(0);
  __syncthreads();

  f32x4 acc[4];
  #pragma unroll
  for (int ct = 0; ct < 4; ++ct) acc[ct] = (f32x4){0.f, 0.f, 0.f, 0.f};
  float m = -INFINITY, l = 0.0f;

  for (int jt = 0; jt < 32; ++jt) {
    const int pp = jt & 1;
    if (jt < 31) {
      stage_load(jt + 1);       // next WhT tile -> regs (written after compute)
      bias_load(bnext, jt + 1); // next bias tile -> regs (latency hidden)
    }

    // e[i, j] = leakyrelu(s1_i + s2_j) + bias_ij   (16 values per lane)
    float ev[16];
    #pragma unroll
    for (int f = 0; f < 2; ++f) {
      const float4 sa = *(const float4*)(s2_lds + jt * 64 + f * 32 + kgrp * 8);
      const float4 sb =
          *(const float4*)(s2_lds + jt * 64 + f * 32 + kgrp * 8 + 4);
      const float4 ba = bcur[f * 2 + 0];
      const float4 bb = bcur[f * 2 + 1];
      const float s2v[8] = {sa.x, sa.y, sa.z, sa.w, sb.x, sb.y, sb.z, sb.w};
      const float bv[8] = {ba.x, ba.y, ba.z, ba.w, bb.x, bb.y, bb.z, bb.w};
      #pragma unroll
      for (int e = 0; e < 8; ++e) {
        float x = s1v + s2v[e];
        x = x > 0.0f ? x : ALPHA * x;
        ev[f * 8 + e] = x + bv[e];
      }
    }

    // row max (in-lane 16, then across the 4 lanes sharing this row)
    float mx = ev[0];
    #pragma unroll
    for (int e = 1; e < 16; ++e) mx = fmaxf(mx, ev[e]);
    mx = fmaxf(mx, __shfl_xor(mx, 16, 64));
    mx = fmaxf(mx, __shfl_xor(mx, 32, 64));
    const float mnew = fmaxf(m, mx);
    const float corr = exp2f((m - mnew) * LOG2E);  // m=-inf first iter -> 0

    float ps = 0.0f;
    s16x8 afrag[2];
    #pragma unroll
    for (int f = 0; f < 2; ++f) {
      #pragma unroll
      for (int e = 0; e < 8; ++e) {
        const float p = exp2f((ev[f * 8 + e] - mnew) * LOG2E);
        ps += p;
        afrag[f][e] = (short)f2bf(p);
      }
    }
    ps += __shfl_xor(ps, 16, 64);
    ps += __shfl_xor(ps, 32, 64);
    l = l * corr + ps;
    m = mnew;

    // rescale accumulator: C-frag rows are kgrp*4+r; corr for row r sits at lane r
    float fc[4];
    #pragma unroll
    for (int r = 0; r < 4; ++r) fc[r] = __shfl(corr, kgrp * 4 + r, 64);
    #pragma unroll
    for (int ct = 0; ct < 4; ++ct) {
      acc[ct][0] *= fc[0];
      acc[ct][1] *= fc[1];
      acc[ct][2] *= fc[2];
      acc[ct][3] *= fc[3];
    }

    // PV: acc[16 rows x 64 cols] += P[16x64] @ Wh[64x64]
    #pragma unroll
    for (int ct = 0; ct < 4; ++ct) {
      const int cc = ct * 16 + arow;
      #pragma unroll
      for (int f = 0; f < 2; ++f) {
        const s16x8 bfrag = *(const s16x8*)((const char*)buf[pp] + cc * 128 +
                                            ((f * 64 + kgrp * 16) ^
                                             ((cc & 7) << 4)));
        // s_nop 1 covers VALU-write -> MFMA-read wait states (inline asm is
        // opaque to the hazard recognizer); chained same-acc MFMAs are legal.
        asm("s_nop 1\n\t"
            "v_mfma_f32_16x16x32_bf16 %0, %1, %2, %0"
            : "+v"(acc[ct])
            : "v"(afrag[f]), "v"(bfrag));
      }
    }

    if (jt < 31) {
      stage_write((jt + 1) & 1);  // other buffer; current readers unaffected
      bcur[0] = bnext[0]; bcur[1] = bnext[1];
      bcur[2] = bnext[2]; bcur[3] = bnext[3];
    }
    __syncthreads();
  }

  // MFMA-write -> VALU-read safety margin before epilogue reads of acc
  asm volatile("s_nop 7\n\ts_nop 7" ::: "memory");

  const float linv = 1.0f / l;
  #pragma unroll
  for (int r = 0; r < 4; ++r) {
    const float li = __shfl(linv, kgrp * 4 + r, 64);
    float* op = out + ((size_t)b * 2048 + i0 + w * 16 + kgrp * 4 + r) * 64;
    #pragma unroll
    for (int ct = 0; ct < 4; ++ct) op[ct * 16 + arow] = acc[ct][r] * li;
  }
}

// ---------------------------------------------------------------------------
extern "C" void kernel_launch(void* const* d_in, const int* in_sizes, int n_in,
                              void* d_out, int out_size, void* d_ws,
                              size_t ws_size, hipStream_t stream) {
  const float* h = (const float*)d_in[0];
  const float* bias = (const float*)d_in[1];
  const float* W = (const float*)d_in[2];
  const float* a1 = (const float*)d_in[3];
  const float* a2 = (const float*)d_in[4];
  float* out = (float*)d_out;

  char* ws = (char*)d_ws;
  unsigned short* whT = (unsigned short*)ws;             // 16*64*2048*2 = 4 MiB
  float* s1 = (float*)(ws + 4 * 1024 * 1024);            // 128 KiB
  float* s2 = (float*)(ws + 4 * 1024 * 1024 + 128 * 1024);  // 128 KiB

  k1_proj<<<dim3(512), dim3(256), 0, stream>>>(h, W, a1, a2, whT, s1, s2);
  k2_attn<<<dim3(512), dim3(256), 0, stream>>>(bias, whT, s1, s2, out);
}